// Round 5
// baseline (3274.066 us; speedup 1.0000x reference)
//
#include <hip/hip_runtime.h>
#include <hip/hip_bf16.h>

#define N_NODES 100000
#define N_EDGES 1600000
#define DIM 256
#define HID 512
#define NLAYERS 5
#define MTILES 782  // ceil(100000/128)

typedef unsigned short u16;
typedef unsigned int u32;
typedef short s16x8 __attribute__((ext_vector_type(8)));  // 8 bf16 (4 VGPRs), MFMA frag
typedef float f32x4 __attribute__((ext_vector_type(4)));

__device__ __forceinline__ float b2f_(u16 u) {
  union { unsigned i; float f; } v;
  v.i = ((unsigned)u) << 16;
  return v.f;
}
__device__ __forceinline__ u16 f2b_(float f) {
  __hip_bfloat16 h = __float2bfloat16(f);  // RNE
  return *reinterpret_cast<u16*>(&h);
}
__device__ __forceinline__ int pk2_(u16 lo, u16 hi) {
  return (int)(((u32)hi << 16) | (u32)lo);
}
// apply y*scl+sft, relu, to 8 bf16 packed in int4; repack as bf16
__device__ __forceinline__ int4 bn_pack_(int4 raw, const float* __restrict__ scl,
                                         const float* __restrict__ sft) {
  const u16* rp = (const u16*)&raw;
  u16 o[8];
#pragma unroll
  for (int q = 0; q < 8; ++q) {
    float v = fmaf(b2f_(rp[q]), scl[q], sft[q]);
    o[q] = f2b_(fmaxf(v, 0.f));
  }
  return make_int4(pk2_(o[0], o[1]), pk2_(o[2], o[3]), pk2_(o[4], o[5]), pk2_(o[6], o[7]));
}

// async global->LDS, 16B per lane. LDS dest is wave-uniform base + lane*16.
__device__ __forceinline__ void gl16_(const u16* g, u16* l) {
  __builtin_amdgcn_global_load_lds(
      (const __attribute__((address_space(1))) void*)g,
      (__attribute__((address_space(3))) void*)l, 16, 0, 0);
}

// swizzled LDS offset (elems) for a [128][32]-bf16 tile stored in 16B chunks:
// physical chunk = logical chunk ^ ((row>>1)&3).  Spreads the 16-row stride-64B
// fragment reads across banks (2-way alias only).  Used by BOTH writers and readers.
__device__ __forceinline__ int lds_off(int row, int g) {
  return row * 32 + (((g ^ (row >> 1)) & 3) << 3);
}

// ---- diagnostic fill (f32): absmax ~= val encodes which host check failed
__global__ void k_fill(float* out, int n, float val) {
  int i = blockIdx.x * 256 + threadIdx.x;
  if (i < n) out[i] = val;
}

__global__ void k_zero(float* p, int n) {
  int i = blockIdx.x * 256 + threadIdx.x;
  if (i < n) p[i] = 0.f;
}

__global__ void k_zeroi(int* p, int n) {
  int i = blockIdx.x * 256 + threadIdx.x;
  if (i < n) p[i] = 0;
}

// h[n,d] = emb[x[n], d].  x = x0[n] + x3[n]: one of d_in[0]/d_in[3] is batch==0.
__global__ void k_gather(const int* x0, const int* x3, const float* emb, float* h) {
  int idx = blockIdx.x * 256 + threadIdx.x;  // exactly N*DIM threads
  int n = idx >> 8, d = idx & 255;
  int t = x0[n] + x3[n];
  h[idx] = emb[(size_t)t * DIM + d];
}

// ====== CSR build (dst -> src list, plus edge_attr permuted into CSR order) ======
__global__ void k_hist(const int* __restrict__ dst, int* __restrict__ deg) {
  int e = blockIdx.x * 256 + threadIdx.x;
  if (e < N_EDGES) atomicAdd(&deg[dst[e]], 1);
}

__global__ void k_scan1(const int* __restrict__ deg, int* __restrict__ offs,
                        int* __restrict__ bsum) {
  __shared__ int sm[256];
  int tid = threadIdx.x;
  int i = blockIdx.x * 256 + tid;
  int v = (i < N_NODES) ? deg[i] : 0;
  sm[tid] = v;
  __syncthreads();
  for (int d = 1; d < 256; d <<= 1) {
    int t = (tid >= d) ? sm[tid - d] : 0;
    __syncthreads();
    sm[tid] += t;
    __syncthreads();
  }
  if (i < N_NODES) offs[i] = sm[tid] - v;  // exclusive within block
  if (tid == 0) bsum[blockIdx.x] = sm[255];
}

__global__ void k_scan2(int* __restrict__ bsum, int nb) {
  __shared__ int sm[512];
  int tid = threadIdx.x;
  int v = (tid < nb) ? bsum[tid] : 0;
  sm[tid] = v;
  __syncthreads();
  for (int d = 1; d < 512; d <<= 1) {
    int t = (tid >= d) ? sm[tid - d] : 0;
    __syncthreads();
    sm[tid] += t;
    __syncthreads();
  }
  if (tid < nb) bsum[tid] = sm[tid] - v;  // exclusive
}

__global__ void k_scan3(int* __restrict__ offs, const int* __restrict__ bsum,
                        int* __restrict__ cur) {
  int i = blockIdx.x * 256 + threadIdx.x;
  if (i < N_NODES) {
    offs[i] += bsum[blockIdx.x];
    cur[i] = 0;
  }
  if (i == 0) offs[N_NODES] = N_EDGES;
}

__global__ void k_fillcsr(const int* __restrict__ dst, const int* __restrict__ srcarr,
                          const float* __restrict__ ea, const int* __restrict__ offs,
                          int* __restrict__ cur, int* __restrict__ elist,
                          float* __restrict__ eaperm) {
  int e = blockIdx.x * 256 + threadIdx.x;
  if (e < N_EDGES) {
    int d = dst[e];
    int p = offs[d] + atomicAdd(&cur[d], 1);
    elist[p] = srcarr[e];
    const float* s = ea + (size_t)e * 7;
    float* o = eaperm + (size_t)p * 7;
#pragma unroll
    for (int k = 0; k < 7; ++k) o[k] = s[k];
  }
}

// ===== fused aggregation: z[n] = (1+eps)*h[n] + sum_in relu(h[s] + ea@We + be)
// BNIN: input rows are RAW prev-layer y2; apply h = relu(y*scl2+sft2) on the fly.
// Output: z written as bf16 hi/lo planes (zh, zl) -- GEMM1's A operand, split done
// here (bit-identical to in-GEMM split, but out of GEMM1's hot loop).
template <int BNIN>
__global__ __launch_bounds__(256) void k_agg(
    const float* __restrict__ hin, const float* __restrict__ eap,
    const int* __restrict__ csr, const int* __restrict__ offs,
    const float* __restrict__ We, const float* __restrict__ be,
    const float* __restrict__ eps_l, const float* __restrict__ scl2,
    const float* __restrict__ sft2, u16* __restrict__ zh, u16* __restrict__ zl) {
  const int lane = threadIdx.x & 63;
  const int n = blockIdx.x * 4 + (threadIdx.x >> 6);  // grid = N/4 exactly
  const int c0 = lane * 4;
  float w[7][4];
#pragma unroll
  for (int k = 0; k < 7; ++k) {
    f32x4 t = *(const f32x4*)&We[k * DIM + c0];
    w[k][0] = t[0]; w[k][1] = t[1]; w[k][2] = t[2]; w[k][3] = t[3];
  }
  const f32x4 bev = *(const f32x4*)&be[c0];
  f32x4 sv, fv;
  if (BNIN) { sv = *(const f32x4*)&scl2[c0]; fv = *(const f32x4*)&sft2[c0]; }
  const f32x4 hn = *(const f32x4*)&hin[(size_t)n * DIM + c0];
  const float e1p = 1.0f + eps_l[0];
  float acc[4];
#pragma unroll
  for (int q = 0; q < 4; ++q) {
    float hv = hn[q];
    if (BNIN) hv = fmaxf(fmaf(hv, sv[q], fv[q]), 0.f);
    acc[q] = e1p * hv;
  }

  auto msg = [&](const f32x4& hs, const float* a) {
#pragma unroll
    for (int q = 0; q < 4; ++q) {
      float hv = hs[q];
      if (BNIN) hv = fmaxf(fmaf(hv, sv[q], fv[q]), 0.f);
      float t = bev[q];
#pragma unroll
      for (int k = 0; k < 7; ++k) t = fmaf(a[k], w[k][q], t);
      acc[q] += fmaxf(hv + t, 0.f);
    }
  };

  const int eb = offs[n], ee = offs[n + 1];
  for (int base = eb; base < ee; base += 64) {
    const int m = min(64, ee - base);
    const int cs = csr[base + min(lane, m - 1)];  // cooperative CSR chunk load
    int e = 0;
    for (; e + 4 <= m; e += 4) {
      const int s0 = __shfl(cs, e);
      const int s1 = __shfl(cs, e + 1);
      const int s2 = __shfl(cs, e + 2);
      const int s3 = __shfl(cs, e + 3);
      const f32x4 h0 = *(const f32x4*)&hin[(size_t)s0 * DIM + c0];
      const f32x4 h1 = *(const f32x4*)&hin[(size_t)s1 * DIM + c0];
      const f32x4 h2 = *(const f32x4*)&hin[(size_t)s2 * DIM + c0];
      const f32x4 h3 = *(const f32x4*)&hin[(size_t)s3 * DIM + c0];
      const float* p0 = eap + (size_t)(base + e) * 7;
      float a0[7], a1[7], a2[7], a3[7];
#pragma unroll
      for (int k = 0; k < 7; ++k) {
        a0[k] = p0[k]; a1[k] = p0[7 + k]; a2[k] = p0[14 + k]; a3[k] = p0[21 + k];
      }
      msg(h0, a0);
      msg(h1, a1);
      msg(h2, a2);
      msg(h3, a3);
    }
    for (; e < m; ++e) {
      const int s0 = __shfl(cs, e);
      const f32x4 h0 = *(const f32x4*)&hin[(size_t)s0 * DIM + c0];
      const float* p0 = eap + (size_t)(base + e) * 7;
      float a0[7];
#pragma unroll
      for (int k = 0; k < 7; ++k) a0[k] = p0[k];
      msg(h0, a0);
    }
  }
  ushort4 zh4, zl4;
#pragma unroll
  for (int q = 0; q < 4; ++q) {
    u16 hh = f2b_(acc[q]);
    float lo = acc[q] - b2f_(hh);
    ((u16*)&zh4)[q] = hh;
    ((u16*)&zl4)[q] = f2b_(lo);
  }
  *(ushort4*)&zh[(size_t)n * DIM + c0] = zh4;
  *(ushort4*)&zl[(size_t)n * DIM + c0] = zl4;
}

// W [K][NC] f32 (row-major) -> Wt hi/lo bf16 [NC][K]  (transposed, split)
template <int K, int NC>
__global__ void k_wconv(const float* __restrict__ W, u16* __restrict__ Wth,
                        u16* __restrict__ Wtl) {
  int idx = blockIdx.x * 256 + threadIdx.x;  // K*NC threads
  int n = idx / K, k = idx - n * K;
  float w = W[(size_t)k * NC + n];
  u16 hh = f2b_(w);
  Wth[idx] = hh;
  Wtl[idx] = f2b_(w - b2f_(hh));
}

// scl = g*rsqrt(var+1e-5), sft = bt - mu*scl  (from col sums)
__global__ void k_bnprep(const float* __restrict__ sum, const float* __restrict__ sq,
                         const float* __restrict__ g, const float* __restrict__ bt,
                         float* __restrict__ scl, float* __restrict__ sft, int n) {
  int j = blockIdx.x * 256 + threadIdx.x;
  if (j < n) {
    const float invN = 1.0f / 100000.0f;
    float mu = sum[j] * invN;
    float var = fmaf(-mu, mu, sq[j] * invN);
    float s = g[j] * rsqrtf(var + 1e-5f);
    scl[j] = s;
    sft[j] = fmaf(-mu, s, bt[j]);
  }
}

// MFMA GEMM: C[M,NC] = A[M,K] @ B[K,NC] + bias, all operands bf16 hi/lo planes.
// NA=2: A = (Ah,Al) planes, staged via global_load_lds (3 mfma products).
// NA=1: A = Ah bf16, reg-staged with optional fused BN1 (bn_pack_), 2 products.
// B (Bth/Btl) always staged via global_load_lds.  LDS layout: linear [128][32]
// per plane with chunk-XOR swizzle (lds_off) applied on source addr / ds_write
// and on fragment reads.  Epilogue: bias add, store, fused column sum/sumsq.
template <int K, int NC, int NA, int OBF, int BN1A>
__global__ __launch_bounds__(256) void k_mgemm(
    const u16* __restrict__ Ah, const u16* __restrict__ Al,
    const u16* __restrict__ Bth, const u16* __restrict__ Btl,
    const float* __restrict__ bias, void* __restrict__ Ov,
    float* __restrict__ colsum, float* __restrict__ colsq,
    const float* __restrict__ ascl, const float* __restrict__ asft) {
  __shared__ u16 As[NA * 128 * 32];
  __shared__ u16 Bs[2 * 128 * 32];
  const int tid = threadIdx.x;
  const int m0 = blockIdx.x * 128;
  const int n0 = blockIdx.y * 128;
  const int lane = tid & 63;
  const int wv = tid >> 6;
  const int wr = (wv >> 1) * 64;  // wave row offset in tile
  const int wc = (wv & 1) * 64;   // wave col offset in tile
  const int lr = lane & 15;       // fragment row/col
  const int g = lane >> 4;        // fragment k-chunk (8-elem units)
  const int sr = tid >> 1;        // reg-staging row (NA==1)
  const int sc = (tid & 1) * 16;  // reg-staging elem offset
  const int ga = min(m0 + sr, N_NODES - 1);  // clamp M-tail (stores guarded)
  // per-lane gload geometry: lane covers (row16 = lane>>2, phys chunk = lane&3)
  const int grow16 = lane >> 2;
  const int glc = (lane & 3) ^ ((lane >> 3) & 3);  // logical chunk at this slot

  const f32x4 z4 = {0.f, 0.f, 0.f, 0.f};
  f32x4 acc[4][4];
#pragma unroll
  for (int i = 0; i < 4; ++i)
#pragma unroll
    for (int j = 0; j < 4; ++j) acc[i][j] = z4;

  for (int k0 = 0; k0 < K; k0 += 32) {
    int4 a0, a1;
    if (NA == 1) {
      const u16* srcp = Ah + (size_t)ga * K + k0 + sc;
      a0 = *(const int4*)(srcp);
      a1 = *(const int4*)(srcp + 8);
      if (BN1A) {
        a0 = bn_pack_(a0, ascl + k0 + sc, asft + k0 + sc);
        a1 = bn_pack_(a1, ascl + k0 + sc + 8, asft + k0 + sc + 8);
      }
    }
    __syncthreads();  // prev iteration's fragment reads done
    if (NA == 2) {
      // wave wv stages one full plane: 0=Ah 1=Al 2=Bh 3=Bl (8 x 1KB calls)
      const u16* gbase;
      u16* lbase;
      int rbase, rclamp;
      if (wv == 0)      { gbase = Ah;  lbase = As;        rbase = m0; rclamp = N_NODES - 1; }
      else if (wv == 1) { gbase = Al;  lbase = As + 4096; rbase = m0; rclamp = N_NODES - 1; }
      else if (wv == 2) { gbase = Bth; lbase = Bs;        rbase = n0; rclamp = 0x7fffffff; }
      else              { gbase = Btl; lbase = Bs + 4096; rbase = n0; rclamp = 0x7fffffff; }
#pragma unroll
      for (int c = 0; c < 8; ++c) {
        int gr = min(rbase + c * 16 + grow16, rclamp);
        gl16_(gbase + (size_t)gr * K + k0 + glc * 8, lbase + c * 512);
      }
    } else {
      // A: swizzled ds_write of the (possibly BN'd) regs
      const int x = (sr >> 1) & 3;
      const int lc0 = (tid & 1) * 2;
      *(int4*)&As[sr * 32 + ((lc0 ^ x) << 3)] = a0;
      *(int4*)&As[sr * 32 + (((lc0 + 1) ^ x) << 3)] = a1;
      // B: wave wv stages plane wv>>1, chunks (wv&1)*4 .. +4
      const u16* gbase = (wv >> 1) ? Btl : Bth;
      u16* lbase = (wv >> 1) ? Bs + 4096 : Bs;
#pragma unroll
      for (int cc = 0; cc < 4; ++cc) {
        int c = (wv & 1) * 4 + cc;
        int gr = n0 + c * 16 + grow16;
        gl16_(gbase + (size_t)gr * K + k0 + glc * 8, lbase + c * 512);
      }
    }
    __syncthreads();  // drains vmcnt(0)+lgkmcnt(0): LDS tiles ready

    // ---- fragments + MFMA
    s16x8 aF[NA][4], bF[2][4];
#pragma unroll
    for (int i = 0; i < 4; ++i) {
      aF[0][i] = *reinterpret_cast<const s16x8*>(&As[lds_off(wr + i * 16 + lr, g)]);
      if (NA == 2)
        aF[1][i] = *reinterpret_cast<const s16x8*>(&As[4096 + lds_off(wr + i * 16 + lr, g)]);
      bF[0][i] = *reinterpret_cast<const s16x8*>(&Bs[lds_off(wc + i * 16 + lr, g)]);
      bF[1][i] = *reinterpret_cast<const s16x8*>(&Bs[4096 + lds_off(wc + i * 16 + lr, g)]);
    }
#pragma unroll
    for (int i = 0; i < 4; ++i)
#pragma unroll
      for (int j = 0; j < 4; ++j) {
        acc[i][j] =
            __builtin_amdgcn_mfma_f32_16x16x32_bf16(aF[0][i], bF[0][j], acc[i][j], 0, 0, 0);
        acc[i][j] =
            __builtin_amdgcn_mfma_f32_16x16x32_bf16(aF[0][i], bF[1][j], acc[i][j], 0, 0, 0);
        if (NA == 2)
          acc[i][j] =
              __builtin_amdgcn_mfma_f32_16x16x32_bf16(aF[1][i], bF[0][j], acc[i][j], 0, 0, 0);
      }
  }

  // ---- epilogue: bias add + store + column stats (D: col=lane&15, row=4*(lane>>4)+reg)
  float bj[4];
#pragma unroll
  for (int j = 0; j < 4; ++j) bj[j] = bias[n0 + wc + j * 16 + lr];
  float ls[4] = {0.f, 0.f, 0.f, 0.f}, lq[4] = {0.f, 0.f, 0.f, 0.f};
#pragma unroll
  for (int i = 0; i < 4; ++i) {
    const int row0 = m0 + wr + i * 16 + (lane >> 4) * 4;
#pragma unroll
    for (int r = 0; r < 4; ++r) {
      const int grow = row0 + r;
      if (grow < N_NODES) {
        const size_t o = (size_t)grow * NC + n0 + wc + lr;
#pragma unroll
        for (int j = 0; j < 4; ++j) {
          float v = acc[i][j][r] + bj[j];
          ls[j] += v;
          lq[j] = fmaf(v, v, lq[j]);
          if (OBF) ((u16*)Ov)[o + j * 16] = f2b_(v);
          else ((float*)Ov)[o + j * 16] = v;
        }
      }
    }
  }
#pragma unroll
  for (int j = 0; j < 4; ++j) {
    float s = ls[j], q = lq[j];
    s += __shfl_xor(s, 16); q += __shfl_xor(q, 16);
    s += __shfl_xor(s, 32); q += __shfl_xor(q, 32);
    if ((lane >> 4) == 0) {
      unsafeAtomicAdd(&colsum[n0 + wc + j * 16 + lr], s);
      unsafeAtomicAdd(&colsq[n0 + wc + j * 16 + lr], q);
    }
  }
}

// O = maybe_relu( (Y - mu) * rsqrt(var+1e-5) * g + b ), elementwise (final layer)
__global__ void k_bn(const void* Y, int y_bf, const float* sum, const float* sq,
                     const float* g, const float* b, int NC_mask,
                     void* O, int o_bf, int do_relu) {
  int idx = blockIdx.x * 256 + threadIdx.x;
  int j = idx & NC_mask;
  const float invN = 1.0f / 100000.0f;
  float mu = sum[j] * invN;
  float var = fmaf(-mu, mu, sq[j] * invN);
  float v = y_bf ? b2f_(((const u16*)Y)[idx]) : ((const float*)Y)[idx];
  v = fmaf((v - mu) * rsqrtf(var + 1e-5f), g[j], b[j]);
  if (do_relu) v = fmaxf(v, 0.f);
  if (o_bf) ((u16*)O)[idx] = f2b_(v);
  else ((float*)O)[idx] = v;
}

extern "C" void kernel_launch(void* const* d_in, const int* in_sizes, int n_in,
                              void* d_out, int out_size, void* d_ws, size_t ws_size,
                              hipStream_t stream) {
  float* out = (float*)d_out;  // output = f32 (reference returns f32)

  // ---- host-side environment verification (sentinel-coded) ----
  const int expected[16] = {100000, 3200000, 11200000, 100000, 76800, 8960, 1280,
                            655360, 2560, 2560, 2560, 655360, 1280, 5, 1280, 1280};
  float sentinel = 0.f;
  if (n_in != 16) sentinel = 60.f;
  else
    for (int i = 0; i < 16; ++i)
      if (in_sizes[i] != expected[i]) { sentinel = 100.f + (float)i; break; }
  if (sentinel == 0.f && out_size != N_NODES * DIM) sentinel = 90.f;

  const size_t ND = (size_t)N_NODES * DIM;  // 25.6M
  const size_t NH = (size_t)N_NODES * HID;  // 51.2M
  const size_t base = 4096 * sizeof(float);
  const size_t need_base = base + 2 * ND * sizeof(float) + NH * sizeof(u16);
  // layout: stats | bufA (ND f32) | bufB (ND f32) | Y1 (NH bf16)
  if (sentinel == 0.f && ws_size < need_base) sentinel = 77.f;
  if (sentinel != 0.f) {
    k_fill<<<(out_size + 255) / 256, 256, 0, stream>>>(out, out_size, sentinel);
    return;
  }

  float* stats = (float*)d_ws;
  float* sum1 = stats;            // [512]
  float* sq1 = sum1 + HID;        // [512]
  float* sum2 = sq1 + HID;        // [256]
  float* sq2 = sum2 + DIM;        // [256]   (sums: 1536 floats, zeroed per layer)
  float* scl1 = stats + 1536;     // [512]
  float* sft1 = scl1 + HID;       // [512]
  float* scl2 = sft1 + HID;       // [256]
  float* sft2 = scl2 + DIM;       // [256]
  float* bufA = stats + 4096;
  float* bufB = bufA + ND;
  u16* Y1 = (u16*)(bufB + ND);  // bf16, NH elems

  // CSR: deg/cur N, offs N+1, bsum 512, pad 1, elist int E (src only), then
  // ea_perm f32 7E.  Tail if room (built once); else overlay on Y1 and rebuild.
  const size_t csr_ints =
      (size_t)N_NODES + (size_t)(N_NODES + 1) + 512 + 1 + (size_t)N_EDGES;
  const size_t csr_bytes = csr_ints * sizeof(int) + (size_t)N_EDGES * 7 * sizeof(float);
  const int csr_tail = ws_size >= need_base + csr_bytes;
  int* degc = csr_tail ? (int*)((char*)d_ws + need_base) : (int*)Y1;
  int* offs = degc + N_NODES;
  int* bsum = offs + N_NODES + 1;
  int* elist = bsum + 512 + 1;
  float* eaperm = (float*)(elist + N_EDGES);
  const int NB_N = (N_NODES + 255) / 256;  // 391
  const int NB_E = N_EDGES / 256;          // 6250

  const int* x0 = (const int*)d_in[0];
  const int* ei = (const int*)d_in[1];
  const float* ea = (const float*)d_in[2];
  const int* x3 = (const int*)d_in[3];
  const float* emb = (const float*)d_in[4];
  const float* We = (const float*)d_in[5];
  const float* be = (const float*)d_in[6];
  const float* W1 = (const float*)d_in[7];
  const float* b1 = (const float*)d_in[8];
  const float* g1 = (const float*)d_in[9];
  const float* bt1 = (const float*)d_in[10];
  const float* W2 = (const float*)d_in[11];
  const float* b2 = (const float*)d_in[12];
  const float* eps = (const float*)d_in[13];
  const float* g_bn = (const float*)d_in[14];
  const float* b_bn = (const float*)d_in[15];

  const int* srcs = ei;            // edge_index[0]
  const int* dsts = ei + N_EDGES;  // edge_index[1]

  const int gridND = (int)(ND / 256);  // 100000

  auto build_csr = [&]() {
    k_zeroi<<<NB_N, 256, 0, stream>>>(degc, N_NODES);
    k_hist<<<NB_E, 256, 0, stream>>>(dsts, degc);
    k_scan1<<<NB_N, 256, 0, stream>>>(degc, offs, bsum);
    k_scan2<<<1, 512, 0, stream>>>(bsum, NB_N);
    k_scan3<<<NB_N, 256, 0, stream>>>(offs, bsum, degc);  // also zeroes cursor
    k_fillcsr<<<NB_E, 256, 0, stream>>>(dsts, srcs, ea, offs, degc, elist, eaperm);
  };

  k_gather<<<gridND, 256, 0, stream>>>(x0, x3, emb, bufA);
  if (csr_tail) build_csr();

  // Ping-pong: IN = B[p] holds raw prev output f32 (or emb); k_agg writes z as
  // bf16 hi/lo planes into B[1-p]; Wt overlays dead IN; GEMM2 writes raw f32 y2
  // into B[1-p] (zh/zl dead after GEMM1).
  float* bufs[2] = {bufA, bufB};
  int p = 0;
  for (int l = 0; l < NLAYERS; ++l) {
    float* IN = bufs[p];
    float* ZB = bufs[1 - p];
    u16* zh = (u16*)ZB;        // [N][256] bf16 hi plane
    u16* zl = zh + ND;         // [N][256] bf16 lo plane (exactly fills ZB)
    u16* Wth = (u16*)IN;       // IN dead after k_agg; 512KB overlay
    u16* Wtl = Wth + (size_t)DIM * HID;

    if (!csr_tail) build_csr();
    k_zero<<<6, 256, 0, stream>>>(stats, 1536);

    // z = (1+eps)*h + segment_sum(relu(h[src]+ea@We+be)), h = relu(BN2(IN)) for l>0
    if (l == 0)
      k_agg<0><<<N_NODES / 4, 256, 0, stream>>>(IN, eaperm, elist, offs,
                                                We + (size_t)l * 7 * DIM,
                                                be + (size_t)l * DIM, eps + l,
                                                nullptr, nullptr, zh, zl);
    else
      k_agg<1><<<N_NODES / 4, 256, 0, stream>>>(IN, eaperm, elist, offs,
                                                We + (size_t)l * 7 * DIM,
                                                be + (size_t)l * DIM, eps + l,
                                                scl2, sft2, zh, zl);

    // Y1(bf16, raw) = z @ W1 + b1; col stats fused into epilogue
    k_wconv<DIM, HID><<<(DIM * HID) / 256, 256, 0, stream>>>(
        W1 + (size_t)l * DIM * HID, Wth, Wtl);
    k_mgemm<DIM, HID, 2, 1, 0><<<dim3(MTILES, HID / 128), 256, 0, stream>>>(
        zh, zl, Wth, Wtl, b1 + (size_t)l * HID, Y1, sum1, sq1, nullptr, nullptr);
    k_bnprep<<<2, 256, 0, stream>>>(sum1, sq1, g1 + (size_t)l * HID,
                                    bt1 + (size_t)l * HID, scl1, sft1, HID);

    // y2(raw f32, into ZB) = relu(BN1(Y1)) @ W2 + b2; BN1 fused in A-stage
    k_wconv<HID, DIM><<<(DIM * HID) / 256, 256, 0, stream>>>(
        W2 + (size_t)l * HID * DIM, Wth, Wtl);
    k_mgemm<HID, DIM, 1, 0, 1><<<dim3(MTILES, DIM / 128), 256, 0, stream>>>(
        Y1, nullptr, Wth, Wtl, b2 + (size_t)l * DIM, ZB, sum2, sq2, scl1, sft1);

    if (l != NLAYERS - 1)
      k_bnprep<<<1, 256, 0, stream>>>(sum2, sq2, g_bn + (size_t)l * DIM,
                                      b_bn + (size_t)l * DIM, scl2, sft2, DIM);
    else
      k_bn<<<gridND, 256, 0, stream>>>(ZB, 0, sum2, sq2, g_bn + (size_t)l * DIM,
                                       b_bn + (size_t)l * DIM, DIM - 1, out, 0, 0);
    p ^= 1;  // next layer's IN = ZB (holds raw y2)
  }
}

// Round 6
// 2877.837 us; speedup vs baseline: 1.1377x; 1.1377x over previous
//
#include <hip/hip_runtime.h>
#include <hip/hip_bf16.h>

#define N_NODES 100000
#define N_EDGES 1600000
#define DIM 256
#define HID 512
#define NLAYERS 5
#define MTILES 782  // ceil(100000/128)

typedef unsigned short u16;
typedef unsigned int u32;
typedef short s16x8 __attribute__((ext_vector_type(8)));  // 8 bf16 (4 VGPRs), MFMA frag
typedef float f32x4 __attribute__((ext_vector_type(4)));

__device__ __forceinline__ float b2f_(u16 u) {
  union { unsigned i; float f; } v;
  v.i = ((unsigned)u) << 16;
  return v.f;
}
__device__ __forceinline__ u16 f2b_(float f) {
  __hip_bfloat16 h = __float2bfloat16(f);  // RNE
  return *reinterpret_cast<u16*>(&h);
}
__device__ __forceinline__ int pk2_(u16 lo, u16 hi) {
  return (int)(((u32)hi << 16) | (u32)lo);
}
// apply y*scl+sft, relu, to 8 bf16 packed in int4; repack as bf16
__device__ __forceinline__ int4 bn_pack_(int4 raw, const float* __restrict__ scl,
                                         const float* __restrict__ sft) {
  const u16* rp = (const u16*)&raw;
  u16 o[8];
#pragma unroll
  for (int q = 0; q < 8; ++q) {
    float v = fmaf(b2f_(rp[q]), scl[q], sft[q]);
    o[q] = f2b_(fmaxf(v, 0.f));
  }
  return make_int4(pk2_(o[0], o[1]), pk2_(o[2], o[3]), pk2_(o[4], o[5]), pk2_(o[6], o[7]));
}

// async global->LDS, 16B per lane. LDS dest is wave-uniform base + lane*16.
__device__ __forceinline__ void gl16_(const u16* g, u16* l) {
  __builtin_amdgcn_global_load_lds(
      (const __attribute__((address_space(1))) void*)g,
      (__attribute__((address_space(3))) void*)l, 16, 0, 0);
}

// swizzled LDS offset (elems) for a [128][32]-bf16 tile stored in 16B chunks:
// physical chunk = logical chunk ^ ((row>>1)&3).  Spreads the 16-row stride-64B
// fragment reads across banks (2-way alias only).  Used by BOTH writers and readers.
__device__ __forceinline__ int lds_off(int row, int g) {
  return row * 32 + (((g ^ (row >> 1)) & 3) << 3);
}

// ---- diagnostic fill (f32): absmax ~= val encodes which host check failed
__global__ void k_fill(float* out, int n, float val) {
  int i = blockIdx.x * 256 + threadIdx.x;
  if (i < n) out[i] = val;
}

__global__ void k_zero(float* p, int n) {
  int i = blockIdx.x * 256 + threadIdx.x;
  if (i < n) p[i] = 0.f;
}

__global__ void k_zeroi(int* p, int n) {
  int i = blockIdx.x * 256 + threadIdx.x;
  if (i < n) p[i] = 0;
}

// h[n,d] = emb[x[n], d].  x = x0[n] + x3[n]: one of d_in[0]/d_in[3] is batch==0.
__global__ void k_gather(const int* x0, const int* x3, const float* emb, float* h) {
  int idx = blockIdx.x * 256 + threadIdx.x;  // exactly N*DIM threads
  int n = idx >> 8, d = idx & 255;
  int t = x0[n] + x3[n];
  h[idx] = emb[(size_t)t * DIM + d];
}

// ====== CSR build (dst -> src list, plus edge_attr permuted into CSR order) ======
__global__ void k_hist(const int* __restrict__ dst, int* __restrict__ deg) {
  int e = blockIdx.x * 256 + threadIdx.x;
  if (e < N_EDGES) atomicAdd(&deg[dst[e]], 1);
}

__global__ void k_scan1(const int* __restrict__ deg, int* __restrict__ offs,
                        int* __restrict__ bsum) {
  __shared__ int sm[256];
  int tid = threadIdx.x;
  int i = blockIdx.x * 256 + tid;
  int v = (i < N_NODES) ? deg[i] : 0;
  sm[tid] = v;
  __syncthreads();
  for (int d = 1; d < 256; d <<= 1) {
    int t = (tid >= d) ? sm[tid - d] : 0;
    __syncthreads();
    sm[tid] += t;
    __syncthreads();
  }
  if (i < N_NODES) offs[i] = sm[tid] - v;  // exclusive within block
  if (tid == 0) bsum[blockIdx.x] = sm[255];
}

__global__ void k_scan2(int* __restrict__ bsum, int nb) {
  __shared__ int sm[512];
  int tid = threadIdx.x;
  int v = (tid < nb) ? bsum[tid] : 0;
  sm[tid] = v;
  __syncthreads();
  for (int d = 1; d < 512; d <<= 1) {
    int t = (tid >= d) ? sm[tid - d] : 0;
    __syncthreads();
    sm[tid] += t;
    __syncthreads();
  }
  if (tid < nb) bsum[tid] = sm[tid] - v;  // exclusive
}

__global__ void k_scan3(int* __restrict__ offs, const int* __restrict__ bsum,
                        int* __restrict__ cur) {
  int i = blockIdx.x * 256 + threadIdx.x;
  if (i < N_NODES) {
    offs[i] += bsum[blockIdx.x];
    cur[i] = 0;
  }
  if (i == 0) offs[N_NODES] = N_EDGES;
}

__global__ void k_fillcsr(const int* __restrict__ dst, const int* __restrict__ srcarr,
                          const float* __restrict__ ea, const int* __restrict__ offs,
                          int* __restrict__ cur, int* __restrict__ elist,
                          float* __restrict__ eaperm) {
  int e = blockIdx.x * 256 + threadIdx.x;
  if (e < N_EDGES) {
    int d = dst[e];
    int p = offs[d] + atomicAdd(&cur[d], 1);
    elist[p] = srcarr[e];
    const float* s = ea + (size_t)e * 7;
    float* o = eaperm + (size_t)p * 7;
#pragma unroll
    for (int k = 0; k < 7; ++k) o[k] = s[k];
  }
}

// ===== fused aggregation: z[n] = (1+eps)*h[n] + sum_in relu(h[s] + ea@We + be)
// BNIN: input rows are RAW prev-layer y2; apply h = relu(y*scl2+sft2) on the fly.
// Output: z written as bf16 hi/lo planes (zh, zl) -- GEMM1's A operand, split done
// here (bit-identical to in-GEMM split, but out of GEMM1's hot loop).
template <int BNIN>
__global__ __launch_bounds__(256) void k_agg(
    const float* __restrict__ hin, const float* __restrict__ eap,
    const int* __restrict__ csr, const int* __restrict__ offs,
    const float* __restrict__ We, const float* __restrict__ be,
    const float* __restrict__ eps_l, const float* __restrict__ scl2,
    const float* __restrict__ sft2, u16* __restrict__ zh, u16* __restrict__ zl) {
  const int lane = threadIdx.x & 63;
  const int n = blockIdx.x * 4 + (threadIdx.x >> 6);  // grid = N/4 exactly
  const int c0 = lane * 4;
  float w[7][4];
#pragma unroll
  for (int k = 0; k < 7; ++k) {
    f32x4 t = *(const f32x4*)&We[k * DIM + c0];
    w[k][0] = t[0]; w[k][1] = t[1]; w[k][2] = t[2]; w[k][3] = t[3];
  }
  const f32x4 bev = *(const f32x4*)&be[c0];
  f32x4 sv, fv;
  if (BNIN) { sv = *(const f32x4*)&scl2[c0]; fv = *(const f32x4*)&sft2[c0]; }
  const f32x4 hn = *(const f32x4*)&hin[(size_t)n * DIM + c0];
  const float e1p = 1.0f + eps_l[0];
  float acc[4];
#pragma unroll
  for (int q = 0; q < 4; ++q) {
    float hv = hn[q];
    if (BNIN) hv = fmaxf(fmaf(hv, sv[q], fv[q]), 0.f);
    acc[q] = e1p * hv;
  }

  auto msg = [&](const f32x4& hs, const float* a) {
#pragma unroll
    for (int q = 0; q < 4; ++q) {
      float hv = hs[q];
      if (BNIN) hv = fmaxf(fmaf(hv, sv[q], fv[q]), 0.f);
      float t = bev[q];
#pragma unroll
      for (int k = 0; k < 7; ++k) t = fmaf(a[k], w[k][q], t);
      acc[q] += fmaxf(hv + t, 0.f);
    }
  };

  const int eb = offs[n], ee = offs[n + 1];
  for (int base = eb; base < ee; base += 64) {
    const int m = min(64, ee - base);
    const int cs = csr[base + min(lane, m - 1)];  // cooperative CSR chunk load
    int e = 0;
    for (; e + 4 <= m; e += 4) {
      const int s0 = __shfl(cs, e);
      const int s1 = __shfl(cs, e + 1);
      const int s2 = __shfl(cs, e + 2);
      const int s3 = __shfl(cs, e + 3);
      const f32x4 h0 = *(const f32x4*)&hin[(size_t)s0 * DIM + c0];
      const f32x4 h1 = *(const f32x4*)&hin[(size_t)s1 * DIM + c0];
      const f32x4 h2 = *(const f32x4*)&hin[(size_t)s2 * DIM + c0];
      const f32x4 h3 = *(const f32x4*)&hin[(size_t)s3 * DIM + c0];
      const float* p0 = eap + (size_t)(base + e) * 7;
      float a0[7], a1[7], a2[7], a3[7];
#pragma unroll
      for (int k = 0; k < 7; ++k) {
        a0[k] = p0[k]; a1[k] = p0[7 + k]; a2[k] = p0[14 + k]; a3[k] = p0[21 + k];
      }
      msg(h0, a0);
      msg(h1, a1);
      msg(h2, a2);
      msg(h3, a3);
    }
    for (; e < m; ++e) {
      const int s0 = __shfl(cs, e);
      const f32x4 h0 = *(const f32x4*)&hin[(size_t)s0 * DIM + c0];
      const float* p0 = eap + (size_t)(base + e) * 7;
      float a0[7];
#pragma unroll
      for (int k = 0; k < 7; ++k) a0[k] = p0[k];
      msg(h0, a0);
    }
  }
  ushort4 zh4, zl4;
#pragma unroll
  for (int q = 0; q < 4; ++q) {
    u16 hh = f2b_(acc[q]);
    float lo = acc[q] - b2f_(hh);
    ((u16*)&zh4)[q] = hh;
    ((u16*)&zl4)[q] = f2b_(lo);
  }
  *(ushort4*)&zh[(size_t)n * DIM + c0] = zh4;
  *(ushort4*)&zl[(size_t)n * DIM + c0] = zl4;
}

// W [K][NC] f32 (row-major) -> Wt hi/lo bf16 [NC][K]  (transposed, split)
template <int K, int NC>
__global__ void k_wconv(const float* __restrict__ W, u16* __restrict__ Wth,
                        u16* __restrict__ Wtl) {
  int idx = blockIdx.x * 256 + threadIdx.x;  // K*NC threads
  int n = idx / K, k = idx - n * K;
  float w = W[(size_t)k * NC + n];
  u16 hh = f2b_(w);
  Wth[idx] = hh;
  Wtl[idx] = f2b_(w - b2f_(hh));
}

// scl = g*rsqrt(var+1e-5), sft = bt - mu*scl  (from col sums)
__global__ void k_bnprep(const float* __restrict__ sum, const float* __restrict__ sq,
                         const float* __restrict__ g, const float* __restrict__ bt,
                         float* __restrict__ scl, float* __restrict__ sft, int n) {
  int j = blockIdx.x * 256 + threadIdx.x;
  if (j < n) {
    const float invN = 1.0f / 100000.0f;
    float mu = sum[j] * invN;
    float var = fmaf(-mu, mu, sq[j] * invN);
    float s = g[j] * rsqrtf(var + 1e-5f);
    scl[j] = s;
    sft[j] = fmaf(-mu, s, bt[j]);
  }
}

// MFMA GEMM: C[M,NC] = A[M,K] @ B[K,NC] + bias, all operands bf16 hi/lo planes.
// NA=2: A = (Ah,Al) planes, staged via global_load_lds (3 mfma products).
// NA=1: A = Ah bf16, reg-staged with optional fused BN1 (bn_pack_), 2 products.
// Flat 1-D grid with XCD-chunked bijective swizzle, n-tile FASTEST within a
// chunk: the NT blocks sharing an A row-panel run adjacently on the SAME XCD,
// so A is fetched ~once from HBM/L3 and re-read from that XCD's L2 (T1).
template <int K, int NC, int NA, int OBF, int BN1A>
__global__ __launch_bounds__(256) void k_mgemm(
    const u16* __restrict__ Ah, const u16* __restrict__ Al,
    const u16* __restrict__ Bth, const u16* __restrict__ Btl,
    const float* __restrict__ bias, void* __restrict__ Ov,
    float* __restrict__ colsum, float* __restrict__ colsq,
    const float* __restrict__ ascl, const float* __restrict__ asft) {
  __shared__ u16 As[NA * 128 * 32];
  __shared__ u16 Bs[2 * 128 * 32];
  constexpr int NT = NC / 128;
  const int nwg = MTILES * NT;
  const int bid = blockIdx.x;
  // bijective XCD-chunk swizzle (m204): XCD k owns a contiguous chunk of the
  // m-major (n-fast) work list; assumes bid%8 -> XCD round-robin (perf-only).
  const int q = nwg >> 3, r = nwg & 7;
  const int xcd = bid & 7, pos = bid >> 3;
  const int lidx = (xcd < r) ? (xcd * (q + 1) + pos)
                             : (r * (q + 1) + (xcd - r) * q + pos);
  const int mt = lidx / NT;
  const int m0 = mt * 128;
  const int n0 = (lidx - mt * NT) * 128;

  const int tid = threadIdx.x;
  const int lane = tid & 63;
  const int wv = tid >> 6;
  const int wr = (wv >> 1) * 64;  // wave row offset in tile
  const int wc = (wv & 1) * 64;   // wave col offset in tile
  const int lr = lane & 15;       // fragment row/col
  const int g = lane >> 4;        // fragment k-chunk (8-elem units)
  const int sr = tid >> 1;        // reg-staging row (NA==1)
  const int sc = (tid & 1) * 16;  // reg-staging elem offset
  const int ga = min(m0 + sr, N_NODES - 1);  // clamp M-tail (stores guarded)
  // per-lane gload geometry: lane covers (row16 = lane>>2, phys chunk = lane&3)
  const int grow16 = lane >> 2;
  const int glc = (lane & 3) ^ ((lane >> 3) & 3);  // logical chunk at this slot

  const f32x4 z4 = {0.f, 0.f, 0.f, 0.f};
  f32x4 acc[4][4];
#pragma unroll
  for (int i = 0; i < 4; ++i)
#pragma unroll
    for (int j = 0; j < 4; ++j) acc[i][j] = z4;

  for (int k0 = 0; k0 < K; k0 += 32) {
    int4 a0, a1;
    if (NA == 1) {
      const u16* srcp = Ah + (size_t)ga * K + k0 + sc;
      a0 = *(const int4*)(srcp);
      a1 = *(const int4*)(srcp + 8);
      if (BN1A) {
        a0 = bn_pack_(a0, ascl + k0 + sc, asft + k0 + sc);
        a1 = bn_pack_(a1, ascl + k0 + sc + 8, asft + k0 + sc + 8);
      }
    }
    __syncthreads();  // prev iteration's fragment reads done
    if (NA == 2) {
      // wave wv stages one full plane: 0=Ah 1=Al 2=Bh 3=Bl (8 x 1KB calls)
      const u16* gbase;
      u16* lbase;
      int rbase, rclamp;
      if (wv == 0)      { gbase = Ah;  lbase = As;        rbase = m0; rclamp = N_NODES - 1; }
      else if (wv == 1) { gbase = Al;  lbase = As + 4096; rbase = m0; rclamp = N_NODES - 1; }
      else if (wv == 2) { gbase = Bth; lbase = Bs;        rbase = n0; rclamp = 0x7fffffff; }
      else              { gbase = Btl; lbase = Bs + 4096; rbase = n0; rclamp = 0x7fffffff; }
#pragma unroll
      for (int c = 0; c < 8; ++c) {
        int gr = min(rbase + c * 16 + grow16, rclamp);
        gl16_(gbase + (size_t)gr * K + k0 + glc * 8, lbase + c * 512);
      }
    } else {
      // A: swizzled ds_write of the (possibly BN'd) regs
      const int x = (sr >> 1) & 3;
      const int lc0 = (tid & 1) * 2;
      *(int4*)&As[sr * 32 + ((lc0 ^ x) << 3)] = a0;
      *(int4*)&As[sr * 32 + (((lc0 + 1) ^ x) << 3)] = a1;
      // B: wave wv stages plane wv>>1, chunks (wv&1)*4 .. +4
      const u16* gbase = (wv >> 1) ? Btl : Bth;
      u16* lbase = (wv >> 1) ? Bs + 4096 : Bs;
#pragma unroll
      for (int cc = 0; cc < 4; ++cc) {
        int c = (wv & 1) * 4 + cc;
        int gr = n0 + c * 16 + grow16;
        gl16_(gbase + (size_t)gr * K + k0 + glc * 8, lbase + c * 512);
      }
    }
    __syncthreads();  // drains vmcnt(0)+lgkmcnt(0): LDS tiles ready

    // ---- fragments + MFMA
    s16x8 aF[NA][4], bF[2][4];
#pragma unroll
    for (int i = 0; i < 4; ++i) {
      aF[0][i] = *reinterpret_cast<const s16x8*>(&As[lds_off(wr + i * 16 + lr, g)]);
      if (NA == 2)
        aF[1][i] = *reinterpret_cast<const s16x8*>(&As[4096 + lds_off(wr + i * 16 + lr, g)]);
      bF[0][i] = *reinterpret_cast<const s16x8*>(&Bs[lds_off(wc + i * 16 + lr, g)]);
      bF[1][i] = *reinterpret_cast<const s16x8*>(&Bs[4096 + lds_off(wc + i * 16 + lr, g)]);
    }
#pragma unroll
    for (int i = 0; i < 4; ++i)
#pragma unroll
      for (int j = 0; j < 4; ++j) {
        acc[i][j] =
            __builtin_amdgcn_mfma_f32_16x16x32_bf16(aF[0][i], bF[0][j], acc[i][j], 0, 0, 0);
        acc[i][j] =
            __builtin_amdgcn_mfma_f32_16x16x32_bf16(aF[0][i], bF[1][j], acc[i][j], 0, 0, 0);
        if (NA == 2)
          acc[i][j] =
              __builtin_amdgcn_mfma_f32_16x16x32_bf16(aF[1][i], bF[0][j], acc[i][j], 0, 0, 0);
      }
  }

  // ---- epilogue: bias add + store + column stats (D: col=lane&15, row=4*(lane>>4)+reg)
  float bj[4];
#pragma unroll
  for (int j = 0; j < 4; ++j) bj[j] = bias[n0 + wc + j * 16 + lr];
  float ls[4] = {0.f, 0.f, 0.f, 0.f}, lq[4] = {0.f, 0.f, 0.f, 0.f};
#pragma unroll
  for (int i = 0; i < 4; ++i) {
    const int row0 = m0 + wr + i * 16 + (lane >> 4) * 4;
#pragma unroll
    for (int r2 = 0; r2 < 4; ++r2) {
      const int grow = row0 + r2;
      if (grow < N_NODES) {
        const size_t o = (size_t)grow * NC + n0 + wc + lr;
#pragma unroll
        for (int j = 0; j < 4; ++j) {
          float v = acc[i][j][r2] + bj[j];
          ls[j] += v;
          lq[j] = fmaf(v, v, lq[j]);
          if (OBF) ((u16*)Ov)[o + j * 16] = f2b_(v);
          else ((float*)Ov)[o + j * 16] = v;
        }
      }
    }
  }
#pragma unroll
  for (int j = 0; j < 4; ++j) {
    float s = ls[j], q2 = lq[j];
    s += __shfl_xor(s, 16); q2 += __shfl_xor(q2, 16);
    s += __shfl_xor(s, 32); q2 += __shfl_xor(q2, 32);
    if ((lane >> 4) == 0) {
      unsafeAtomicAdd(&colsum[n0 + wc + j * 16 + lr], s);
      unsafeAtomicAdd(&colsq[n0 + wc + j * 16 + lr], q2);
    }
  }
}

// O = maybe_relu( (Y - mu) * rsqrt(var+1e-5) * g + b ), elementwise (final layer)
__global__ void k_bn(const void* Y, int y_bf, const float* sum, const float* sq,
                     const float* g, const float* b, int NC_mask,
                     void* O, int o_bf, int do_relu) {
  int idx = blockIdx.x * 256 + threadIdx.x;
  int j = idx & NC_mask;
  const float invN = 1.0f / 100000.0f;
  float mu = sum[j] * invN;
  float var = fmaf(-mu, mu, sq[j] * invN);
  float v = y_bf ? b2f_(((const u16*)Y)[idx]) : ((const float*)Y)[idx];
  v = fmaf((v - mu) * rsqrtf(var + 1e-5f), g[j], b[j]);
  if (do_relu) v = fmaxf(v, 0.f);
  if (o_bf) ((u16*)O)[idx] = f2b_(v);
  else ((float*)O)[idx] = v;
}

extern "C" void kernel_launch(void* const* d_in, const int* in_sizes, int n_in,
                              void* d_out, int out_size, void* d_ws, size_t ws_size,
                              hipStream_t stream) {
  float* out = (float*)d_out;  // output = f32 (reference returns f32)

  // ---- host-side environment verification (sentinel-coded) ----
  const int expected[16] = {100000, 3200000, 11200000, 100000, 76800, 8960, 1280,
                            655360, 2560, 2560, 2560, 655360, 1280, 5, 1280, 1280};
  float sentinel = 0.f;
  if (n_in != 16) sentinel = 60.f;
  else
    for (int i = 0; i < 16; ++i)
      if (in_sizes[i] != expected[i]) { sentinel = 100.f + (float)i; break; }
  if (sentinel == 0.f && out_size != N_NODES * DIM) sentinel = 90.f;

  const size_t ND = (size_t)N_NODES * DIM;  // 25.6M
  const size_t NH = (size_t)N_NODES * HID;  // 51.2M
  const size_t base = 4096 * sizeof(float);
  const size_t need_base = base + 2 * ND * sizeof(float) + NH * sizeof(u16);
  // layout: stats | bufA (ND f32) | bufB (ND f32) | Y1 (NH bf16)
  if (sentinel == 0.f && ws_size < need_base) sentinel = 77.f;
  if (sentinel != 0.f) {
    k_fill<<<(out_size + 255) / 256, 256, 0, stream>>>(out, out_size, sentinel);
    return;
  }

  float* stats = (float*)d_ws;
  float* sum1 = stats;            // [512]
  float* sq1 = sum1 + HID;        // [512]
  float* sum2 = sq1 + HID;        // [256]
  float* sq2 = sum2 + DIM;        // [256]   (sums: 1536 floats, zeroed per layer)
  float* scl1 = stats + 1536;     // [512]
  float* sft1 = scl1 + HID;       // [512]
  float* scl2 = sft1 + HID;       // [256]
  float* sft2 = scl2 + DIM;       // [256]
  float* bufA = stats + 4096;
  float* bufB = bufA + ND;
  u16* Y1 = (u16*)(bufB + ND);  // bf16, NH elems

  // CSR: deg/cur N, offs N+1, bsum 512, pad 1, elist int E (src only), then
  // ea_perm f32 7E.  Tail if room (built once); else overlay on Y1 and rebuild.
  const size_t csr_ints =
      (size_t)N_NODES + (size_t)(N_NODES + 1) + 512 + 1 + (size_t)N_EDGES;
  const size_t csr_bytes = csr_ints * sizeof(int) + (size_t)N_EDGES * 7 * sizeof(float);
  const int csr_tail = ws_size >= need_base + csr_bytes;
  int* degc = csr_tail ? (int*)((char*)d_ws + need_base) : (int*)Y1;
  int* offs = degc + N_NODES;
  int* bsum = offs + N_NODES + 1;
  int* elist = bsum + 512 + 1;
  float* eaperm = (float*)(elist + N_EDGES);
  const int NB_N = (N_NODES + 255) / 256;  // 391
  const int NB_E = N_EDGES / 256;          // 6250

  const int* x0 = (const int*)d_in[0];
  const int* ei = (const int*)d_in[1];
  const float* ea = (const float*)d_in[2];
  const int* x3 = (const int*)d_in[3];
  const float* emb = (const float*)d_in[4];
  const float* We = (const float*)d_in[5];
  const float* be = (const float*)d_in[6];
  const float* W1 = (const float*)d_in[7];
  const float* b1 = (const float*)d_in[8];
  const float* g1 = (const float*)d_in[9];
  const float* bt1 = (const float*)d_in[10];
  const float* W2 = (const float*)d_in[11];
  const float* b2 = (const float*)d_in[12];
  const float* eps = (const float*)d_in[13];
  const float* g_bn = (const float*)d_in[14];
  const float* b_bn = (const float*)d_in[15];

  const int* srcs = ei;            // edge_index[0]
  const int* dsts = ei + N_EDGES;  // edge_index[1]

  const int gridND = (int)(ND / 256);  // 100000

  auto build_csr = [&]() {
    k_zeroi<<<NB_N, 256, 0, stream>>>(degc, N_NODES);
    k_hist<<<NB_E, 256, 0, stream>>>(dsts, degc);
    k_scan1<<<NB_N, 256, 0, stream>>>(degc, offs, bsum);
    k_scan2<<<1, 512, 0, stream>>>(bsum, NB_N);
    k_scan3<<<NB_N, 256, 0, stream>>>(offs, bsum, degc);  // also zeroes cursor
    k_fillcsr<<<NB_E, 256, 0, stream>>>(dsts, srcs, ea, offs, degc, elist, eaperm);
  };

  k_gather<<<gridND, 256, 0, stream>>>(x0, x3, emb, bufA);
  if (csr_tail) build_csr();

  // Ping-pong: IN = B[p] holds raw prev output f32 (or emb); k_agg writes z as
  // bf16 hi/lo planes into B[1-p]; Wt overlays dead IN; GEMM2 writes raw f32 y2
  // into B[1-p] (zh/zl dead after GEMM1).
  float* bufs[2] = {bufA, bufB};
  int p = 0;
  for (int l = 0; l < NLAYERS; ++l) {
    float* IN = bufs[p];
    float* ZB = bufs[1 - p];
    u16* zh = (u16*)ZB;        // [N][256] bf16 hi plane
    u16* zl = zh + ND;         // [N][256] bf16 lo plane (exactly fills ZB)
    u16* Wth = (u16*)IN;       // IN dead after k_agg; 512KB overlay
    u16* Wtl = Wth + (size_t)DIM * HID;

    if (!csr_tail) build_csr();
    k_zero<<<6, 256, 0, stream>>>(stats, 1536);

    // z = (1+eps)*h + segment_sum(relu(h[src]+ea@We+be)), h = relu(BN2(IN)) for l>0
    if (l == 0)
      k_agg<0><<<N_NODES / 4, 256, 0, stream>>>(IN, eaperm, elist, offs,
                                                We + (size_t)l * 7 * DIM,
                                                be + (size_t)l * DIM, eps + l,
                                                nullptr, nullptr, zh, zl);
    else
      k_agg<1><<<N_NODES / 4, 256, 0, stream>>>(IN, eaperm, elist, offs,
                                                We + (size_t)l * 7 * DIM,
                                                be + (size_t)l * DIM, eps + l,
                                                scl2, sft2, zh, zl);

    // Y1(bf16, raw) = z @ W1 + b1; col stats fused into epilogue
    k_wconv<DIM, HID><<<(DIM * HID) / 256, 256, 0, stream>>>(
        W1 + (size_t)l * DIM * HID, Wth, Wtl);
    k_mgemm<DIM, HID, 2, 1, 0><<<MTILES * (HID / 128), 256, 0, stream>>>(
        zh, zl, Wth, Wtl, b1 + (size_t)l * HID, Y1, sum1, sq1, nullptr, nullptr);
    k_bnprep<<<2, 256, 0, stream>>>(sum1, sq1, g1 + (size_t)l * HID,
                                    bt1 + (size_t)l * HID, scl1, sft1, HID);

    // y2(raw f32, into ZB) = relu(BN1(Y1)) @ W2 + b2; BN1 fused in A-stage
    k_wconv<HID, DIM><<<(DIM * HID) / 256, 256, 0, stream>>>(
        W2 + (size_t)l * HID * DIM, Wth, Wtl);
    k_mgemm<HID, DIM, 1, 0, 1><<<MTILES * (DIM / 128), 256, 0, stream>>>(
        Y1, nullptr, Wth, Wtl, b2 + (size_t)l * DIM, ZB, sum2, sq2, scl1, sft1);

    if (l != NLAYERS - 1)
      k_bnprep<<<1, 256, 0, stream>>>(sum2, sq2, g_bn + (size_t)l * DIM,
                                      b_bn + (size_t)l * DIM, scl2, sft2, DIM);
    else
      k_bn<<<gridND, 256, 0, stream>>>(ZB, 0, sum2, sq2, g_bn + (size_t)l * DIM,
                                       b_bn + (size_t)l * DIM, DIM - 1, out, 0, 0);
    p ^= 1;  // next layer's IN = ZB (holds raw y2)
  }
}